// Round 3
// baseline (485.330 us; speedup 1.0000x reference)
//
#include <hip/hip_runtime.h>

// Problem constants (fixed by the reference)
#define KS   5      // kernel size
#define DIL  2      // dilation
#define PAD  4      // (KS/2)*DIL
#define B_   4
#define C_   32
#define P_   8
#define OUTC 24     // DYNAMIC_SIZE
#define H_   512
#define W_   512
#define HW   (H_ * W_)

#define LROW 528    // LDS row stride in floats: [0..3]=left pad, [4..515]=row, [516..519]=right pad

typedef float4 f4;
typedef float f4v __attribute__((ext_vector_type(4)));

// v3: one block (128 thr) = one output row; 4 px/thread.
// Per plane/channel: stage the 5 dilated tap rows into LDS with coalesced
// dwordx4 loads (issued one iteration early, T14 style, so HBM/L2 latency
// hides under the previous plane's compute), then read each thread's
// 12-float window as 3 contiguous ds_read_b128 (conflict-free pattern) and
// extract the 5 dilated taps at compile-time offsets.
__global__ __launch_bounds__(128, 3)
void bilateral_lds(const float* __restrict__ inp,   // (B, C, H, W)
                   const float* __restrict__ par,   // (B, P, H, W)
                   float* __restrict__ out)         // (B, OUTC, H, W)
{
    __shared__ float lds[KS][LROW];

    // XCD-aware bijective swizzle (2048 % 8 == 0): each XCD owns 256
    // consecutive rows so the 9-row dy-reuse window stays in its L2/L3 path.
    const int nwg = gridDim.x;                   // 2048
    const int bid = blockIdx.x;
    const int sb  = (bid & 7) * (nwg >> 3) + (bid >> 3);
    const int b = sb >> 9;                       // 512 rows per image
    const int y = sb & (H_ - 1);

    const int u  = threadIdx.x;                  // 0..127
    const int x0 = u << 2;                       // 4 px per thread

    const float* __restrict__ parb = par + (size_t)b * P_ * HW;
    const float* __restrict__ inpb = inp + (size_t)b * C_ * HW;
    float* __restrict__ outb       = out + (size_t)b * OUTC * HW;

    // per-dy clamped row offsets + validity — wave-uniform (SGPR)
    int  rowoff[KS];
    bool rowok[KS];
#pragma unroll
    for (int d = 0; d < KS; ++d) {
        const int yy = y + d * DIL - PAD;
        rowok[d]  = (yy >= 0) & (yy < H_);
        rowoff[d] = min(max(yy, 0), H_ - 1) * W_;
    }

    // zero pad columns once: masked taps read them, values must be finite
    if (u < 4) {
#pragma unroll
        for (int r = 0; r < KS; ++r) { lds[r][u] = 0.f; lds[r][516 + u] = 0.f; }
    }

    // ---- staging: issue loads early (regs), commit to LDS late ----
    f4 stg[KS];
    auto issue = [&](const float* plane) {
#pragma unroll
        for (int r = 0; r < KS; ++r)
            stg[r] = *(const f4*)(plane + rowoff[r] + x0);   // 1 KiB/wave/instr
    };
    auto commit = [&]() {
#pragma unroll
        for (int r = 0; r < KS; ++r)
            *(f4*)&lds[r][4 + x0] = stg[r];
    };

    // ---- d2 init: 0 for valid taps, BIG for invalid (exp -> exactly 0) ----
    f4 d2[KS * KS];
#pragma unroll
    for (int d = 0; d < KS; ++d) {
#pragma unroll
        for (int e = 0; e < KS; ++e) {
            const int xb = x0 + e * DIL - PAD;
            f4 v;
            v.x = (rowok[d] && (xb + 0 >= 0) && (xb + 0 < W_)) ? 0.f : 1e5f;
            v.y = (rowok[d] && (xb + 1 >= 0) && (xb + 1 < W_)) ? 0.f : 1e5f;
            v.z = (rowok[d] && (xb + 2 >= 0) && (xb + 2 < W_)) ? 0.f : 1e5f;
            v.w = (rowok[d] && (xb + 3 >= 0) && (xb + 3 < W_)) ? 0.f : 1e5f;
            d2[d * KS + e] = v;
        }
    }

    // ---- weight phase: 8 guide planes ----
    issue(parb);                                 // prologue: plane 0
    f4 pc;                                       // center params (4 px), per plane
#pragma unroll 1
    for (int p = 0; p < P_; ++p) {
        if (p) __syncthreads();                  // prev compute done reading LDS
        commit();
        issue((p < P_ - 1) ? (parb + (size_t)(p + 1) * HW) : inpb); // next (seam: channel 0)
        __syncthreads();                         // staged rows visible
        // d order {2,0,1,3,4}: center row first so pc comes free from its window
#pragma unroll
        for (int dd = 0; dd < KS; ++dd) {
            const int d = (dd == 0) ? 2 : ((dd <= 2) ? (dd - 1) : dd);
            const f4 w0 = *(const f4*)&lds[d][x0];        // window idx [x0, x0+12)
            const f4 w1 = *(const f4*)&lds[d][x0 + 4];
            const f4 w2 = *(const f4*)&lds[d][x0 + 8];
            if (dd == 0) pc = w1;                         // center px = win[4..7]
            const float win[12] = {w0.x, w0.y, w0.z, w0.w,
                                   w1.x, w1.y, w1.z, w1.w,
                                   w2.x, w2.y, w2.z, w2.w};
#pragma unroll
            for (int e = 0; e < KS; ++e) {
                f4& a = d2[d * KS + e];
                const int o = 2 * e;
                float t;
                t = pc.x - win[o + 0]; a.x += t * t;
                t = pc.y - win[o + 1]; a.y += t * t;
                t = pc.z - win[o + 2]; a.z += t * t;
                t = pc.w - win[o + 3]; a.w += t * t;
            }
        }
    }

    // ---- exp; normalization deferred to the store (matches reference) ----
    f4 w[KS * KS];
    float s0 = 0.f, s1 = 0.f, s2 = 0.f, s3 = 0.f;
#pragma unroll
    for (int t = 0; t < KS * KS; ++t) {
        w[t].x = __expf(-d2[t].x);
        w[t].y = __expf(-d2[t].y);
        w[t].z = __expf(-d2[t].z);
        w[t].w = __expf(-d2[t].w);
        s0 += w[t].x; s1 += w[t].y; s2 += w[t].z; s3 += w[t].w;
    }
    const f4 inv = make_float4(1.f / (s0 + 1e-8f), 1.f / (s1 + 1e-8f),
                               1.f / (s2 + 1e-8f), 1.f / (s3 + 1e-8f));

    // ---- channel phase: 24 data channels ----
    const size_t obase = (size_t)y * W_ + x0;
#pragma unroll 1
    for (int c = 0; c < OUTC; ++c) {
        __syncthreads();                         // prev compute done reading LDS
        commit();
        if (c < OUTC - 1) issue(inpb + (size_t)(c + 1) * HW);
        __syncthreads();                         // staged rows visible
        f4 acc = make_float4(0.f, 0.f, 0.f, 0.f);
#pragma unroll
        for (int d = 0; d < KS; ++d) {
            const f4 w0 = *(const f4*)&lds[d][x0];
            const f4 w1 = *(const f4*)&lds[d][x0 + 4];
            const f4 w2 = *(const f4*)&lds[d][x0 + 8];
            const float win[12] = {w0.x, w0.y, w0.z, w0.w,
                                   w1.x, w1.y, w1.z, w1.w,
                                   w2.x, w2.y, w2.z, w2.w};
#pragma unroll
            for (int e = 0; e < KS; ++e) {
                const f4 ww = w[d * KS + e];
                const int o = 2 * e;
                acc.x += ww.x * win[o + 0];
                acc.y += ww.y * win[o + 1];
                acc.z += ww.z * win[o + 2];
                acc.w += ww.w * win[o + 3];
            }
        }
        acc.x *= inv.x; acc.y *= inv.y; acc.z *= inv.z; acc.w *= inv.w;
        // nt store: don't let the 96 MB output stream evict input rows from L2
        __builtin_nontemporal_store(*(const f4v*)&acc, (f4v*)(outb + (size_t)c * HW + obase));
    }
}

extern "C" void kernel_launch(void* const* d_in, const int* in_sizes, int n_in,
                              void* d_out, int out_size, void* d_ws, size_t ws_size,
                              hipStream_t stream) {
    const float* inp = (const float*)d_in[0];   // (4,32,512,512) fp32
    const float* par = (const float*)d_in[1];   // (4,8,512,512) fp32
    float* out = (float*)d_out;                 // (4,24,512,512) fp32

    dim3 block(128);
    dim3 grid(B_ * H_);                         // 2048 blocks: one row each
    bilateral_lds<<<grid, block, 0, stream>>>(inp, par, out);
}

// Round 4
// 268.444 us; speedup vs baseline: 1.8079x; 1.8079x over previous
//
#include <hip/hip_runtime.h>

// Problem constants (fixed by the reference)
#define KS   5      // kernel size
#define DIL  2      // dilation
#define PAD  4      // (KS/2)*DIL
#define B_   4
#define C_   32
#define P_   8
#define OUTC 24     // DYNAMIC_SIZE
#define H_   512
#define W_   512
#define HW   (H_ * W_)
#define NP   (P_ + OUTC)   // 32 staged planes: 8 guide then 24 data
#define LROW 528           // LDS row stride in floats: [0..3] pad | [4..515] row | [516..519] pad

typedef float2 f2;

// v4: one block (256 thr) = one output row; 2 px/thread (float2 state -> no
// spill, ~85 VGPRs). Per plane: stage the 5 dilated tap rows into a
// DOUBLE-BUFFERED LDS slab (5 coalesced dwordx2 per thread, issued one plane
// early so L2/L3 latency hides under the previous plane's compute), one
// barrier per plane. Taps come straight out of LDS as 25 ds_read_b64 with
// compile-time offset immediates. Plain stores (v3's NT stores caused 4x
// write amplification).
__global__ __launch_bounds__(256, 4)
void bilateral_db(const float* __restrict__ inp,   // (B, C, H, W)
                  const float* __restrict__ par,   // (B, P, H, W)
                  float* __restrict__ out)         // (B, OUTC, H, W)
{
    __shared__ float lds[2][KS][LROW];             // 21120 B

    // XCD-aware bijective swizzle (2048 % 8 == 0): each XCD owns 256
    // consecutive rows -> dy-overlap re-reads hit its own L2.
    const int nwg = gridDim.x;                     // 2048
    const int bid = blockIdx.x;
    const int sb  = (bid & 7) * (nwg >> 3) + (bid >> 3);
    const int b = sb >> 9;                         // 512 rows per image
    const int y = sb & (H_ - 1);

    const int u  = threadIdx.x;                    // 0..255
    const int x0 = u << 1;                         // 2 px per thread

    const float* __restrict__ parb = par + (size_t)b * P_ * HW;
    const float* __restrict__ inpb = inp + (size_t)b * C_ * HW;
    float* __restrict__ outb       = out + (size_t)b * OUTC * HW;

    // per-dy clamped row offsets + validity — wave-uniform (SGPR)
    int  rowoff[KS];
    bool rowok[KS];
#pragma unroll
    for (int d = 0; d < KS; ++d) {
        const int yy = y + d * DIL - PAD;
        rowok[d]  = (yy >= 0) & (yy < H_);
        rowoff[d] = min(max(yy, 0), H_ - 1) * W_;
    }

    // zero pad columns of BOTH buffers once (masked taps read them; the
    // values feed zero-weight taps so they only need to be finite)
    if (u < 8) {
        const int bi = u >> 2, col = u & 3;
#pragma unroll
        for (int r = 0; r < KS; ++r) {
            lds[bi][r][col] = 0.f;
            lds[bi][r][516 + col] = 0.f;
        }
    }

    // ---- staging: issue loads early (regs), commit to LDS late ----
    f2 stg[KS];
    auto issue = [&](int t) {                      // t = plane index 0..NP-1
        const float* plane = (t < P_) ? (parb + (size_t)t * HW)
                                      : (inpb + (size_t)(t - P_) * HW);
#pragma unroll
        for (int r = 0; r < KS; ++r)
            stg[r] = *(const f2*)(plane + rowoff[r] + x0);   // 2 KiB/block/row
    };
    auto commit = [&](int bi) {
#pragma unroll
        for (int r = 0; r < KS; ++r)
            *(f2*)&lds[bi][r][4 + x0] = stg[r];
    };

    // ---- d2 init: 0 for valid taps, BIG for invalid (exp -> exactly 0) ----
    f2 d2[KS * KS];
#pragma unroll
    for (int d = 0; d < KS; ++d) {
#pragma unroll
        for (int e = 0; e < KS; ++e) {
            const int xb = x0 + e * DIL - PAD;
            d2[d * KS + e].x = (rowok[d] && (xb + 0 >= 0) && (xb + 0 < W_)) ? 0.f : 1e5f;
            d2[d * KS + e].y = (rowok[d] && (xb + 1 >= 0) && (xb + 1 < W_)) ? 0.f : 1e5f;
        }
    }

    // ---- pipeline prologue: buf0 <- plane0; plane1 in flight ----
    issue(0);
    commit(0);
    issue(1);

    // ---- weight phase: 8 guide planes, one barrier per plane ----
#pragma unroll 1
    for (int t = 0; t < P_; ++t) {
        __syncthreads();                 // buf[t&1] committed by all waves;
                                         // buf[(t+1)&1] no longer being read
        commit((t + 1) & 1);             // waits vmcnt for plane t+1 (issued last iter)
        issue(t + 2);                    // planes 2..9 (seam into data channels)
        const int bi = t & 1;
        const f2 pc = *(const f2*)&lds[bi][2][4 + x0];   // center tap (d=2,e=2)
#pragma unroll
        for (int d = 0; d < KS; ++d) {
#pragma unroll
            for (int e = 0; e < KS; ++e) {
                if (d == 2 && e == 2) continue;          // center: d2 stays 0
                const f2 v = *(const f2*)&lds[bi][d][x0 + 2 * e]; // float (x0+2e-4)+4
                const float tx = pc.x - v.x;
                const float ty = pc.y - v.y;
                d2[d * KS + e].x += tx * tx;
                d2[d * KS + e].y += ty * ty;
            }
        }
    }

    // ---- exp; normalization deferred to the store ----
    f2 w[KS * KS];
    float sx = 0.f, sy = 0.f;
#pragma unroll
    for (int q = 0; q < KS * KS; ++q) {
        w[q].x = __expf(-d2[q].x);       // d2[12]==0 -> w==1 (center), correct
        w[q].y = __expf(-d2[q].y);
        sx += w[q].x;
        sy += w[q].y;
    }
    const float ivx = 1.f / (sx + 1e-8f);
    const float ivy = 1.f / (sy + 1e-8f);

    // ---- channel phase: 24 data channels ----
    const size_t obase = (size_t)y * W_ + x0;
#pragma unroll 1
    for (int t = P_; t < NP; ++t) {
        __syncthreads();
        if (t + 1 < NP) {
            commit((t + 1) & 1);
            if (t + 2 < NP) issue(t + 2);
        }
        const int bi = t & 1;
        float ax = 0.f, ay = 0.f;
#pragma unroll
        for (int d = 0; d < KS; ++d) {
#pragma unroll
            for (int e = 0; e < KS; ++e) {
                const f2 v = *(const f2*)&lds[bi][d][x0 + 2 * e];
                ax += w[d * KS + e].x * v.x;
                ay += w[d * KS + e].y * v.y;
            }
        }
        f2 o;
        o.x = ax * ivx;
        o.y = ay * ivy;
        *(f2*)(outb + (size_t)(t - P_) * HW + obase) = o;   // plain store
    }
}

extern "C" void kernel_launch(void* const* d_in, const int* in_sizes, int n_in,
                              void* d_out, int out_size, void* d_ws, size_t ws_size,
                              hipStream_t stream) {
    const float* inp = (const float*)d_in[0];   // (4,32,512,512) fp32
    const float* par = (const float*)d_in[1];   // (4,8,512,512) fp32
    float* out = (float*)d_out;                 // (4,24,512,512) fp32

    dim3 block(256);
    dim3 grid(B_ * H_);                         // 2048 blocks: one row each
    bilateral_db<<<grid, block, 0, stream>>>(inp, par, out);
}